// Round 8
// baseline (4371.209 us; speedup 1.0000x reference)
//
#include <hip/hip_runtime.h>
#include <hip/hip_bf16.h>

// Problem constants
#define B_     32
#define DL_    1024
#define L_     196
#define OUT_   512
#define G4_    2048
#define T_     256      // NS*NW total timesteps
#define VOCAB_ 3266
#define NWG_REC 384     // 2 WG/CU: LDS 49408 B <= 65536 (128 KiB/CU budget / 2)
#define NWG_L1  128
#define NSLOT_  16
#define SLOT_TGT_ (NWG_REC / NSLOT_)   // 24 arrivals per slot
#define SLOT_STRIDE_ 16                // one 64B line per slot

// workspace layout (bytes)
#define OFF_BAR 0
#define BAR_BYTES_ (T_ * NSLOT_ * SLOT_STRIDE_ * 4)
#define OFF_X   (OFF_BAR + BAR_BYTES_)              // [32][1024] f32
#define OFF_XW1 (OFF_X + B_*DL_*4)                  // [32][2048] f32
#define OFF_B2  (OFF_XW1 + B_*G4_*4)                // [2048] f32
#define OFF_HP  (OFF_B2 + G4_*4)                    // ping-pong h: [2][32][512] f16
#define OFF_H1  (OFF_HP + 2*B_*OUT_*2)              // [257][32][512] f16
#define H1_BYTES_ ((size_t)(T_+1)*B_*OUT_*2)

typedef _Float16 h8 __attribute__((ext_vector_type(8)));

// f16-source f32-accumulate dot (v_fma_mix_f32); semantics unambiguous.
__device__ __forceinline__ float dot8(h8 a, h8 b, float s) {
  #pragma unroll
  for (int i = 0; i < 8; ++i) s = fmaf((float)a[i], (float)b[i], s);
  return s;
}

__device__ __forceinline__ float sigmf(float v) { return 1.0f / (1.0f + __expf(-v)); }

__device__ __forceinline__ unsigned short f2h(float f) {
  union { _Float16 h; unsigned short u; } c;
  c.h = (_Float16)f;
  return c.u;
}

// coherent (bypass L1/L2 -> L3 coherent point) 8B load/store — proven R4/R7
__device__ __forceinline__ unsigned long long ld8(const unsigned long long* p) {
  return __hip_atomic_load(p, __ATOMIC_RELAXED, __HIP_MEMORY_SCOPE_AGENT);
}
__device__ __forceinline__ void st8(unsigned long long* p, unsigned long long v) {
  __hip_atomic_store(p, v, __ATOMIC_RELAXED, __HIP_MEMORY_SCOPE_AGENT);
}

// Fence-free phase barrier; watchdog frees GPU on co-residency loss.
__device__ __forceinline__ void phase_barrier(unsigned int* bar, int q, int wg, unsigned* dead) {
  const int tid = threadIdx.x;
  if (tid == 0) {
    asm volatile("s_waitcnt vmcnt(0)" ::: "memory");
    __hip_atomic_fetch_add(&bar[(q * NSLOT_ + (wg & (NSLOT_ - 1))) * SLOT_STRIDE_], 1u,
                           __ATOMIC_RELAXED, __HIP_MEMORY_SCOPE_AGENT);
  }
  if (tid < NSLOT_ && !*dead) {
    unsigned polls = 0;
    while (__hip_atomic_load(&bar[(q * NSLOT_ + tid) * SLOT_STRIDE_], __ATOMIC_RELAXED,
                             __HIP_MEMORY_SCOPE_AGENT) < (unsigned)SLOT_TGT_) {
      __builtin_amdgcn_s_sleep(2);
      if (++polls > 10000000u) { *dead = 1; break; }
    }
  }
  __syncthreads();
}

// x[b][d] = sum_i local_features[b][d][i]
__global__ __launch_bounds__(256) void k_rowsum(const float* __restrict__ lf, float* __restrict__ x) {
  int t = blockIdx.x * 256 + threadIdx.x;
  const float4* p = (const float4*)(lf + (size_t)t * L_);
  float s = 0.f;
  #pragma unroll
  for (int i = 0; i < 49; ++i) { float4 v = p[i]; s += (v.x + v.y) + (v.z + v.w); }
  x[t] = s;
}

// xw1[b][j] = x[b]·W_ih1[j] + b_ih1[j] + b_hh1[j];  bias2[j] = b_ih2[j]+b_hh2[j]
__global__ __launch_bounds__(256) void k_xw1(const float* __restrict__ x, const float* __restrict__ Wih1,
                                             const float* __restrict__ bih1, const float* __restrict__ bhh1,
                                             const float* __restrict__ bih2, const float* __restrict__ bhh2,
                                             float* __restrict__ xw1, float* __restrict__ bias2) {
  int t = blockIdx.x * 256 + threadIdx.x;
  int b = t >> 11, j = t & (G4_ - 1);
  const float4* xp = (const float4*)(x + (size_t)b * DL_);
  const float4* wp = (const float4*)(Wih1 + (size_t)j * DL_);
  float s = 0.f;
  #pragma unroll 8
  for (int i = 0; i < DL_ / 4; ++i) {
    float4 a = xp[i], w = wp[i];
    s += a.x * w.x + a.y * w.y + a.z * w.z + a.w * w.w;
  }
  xw1[t] = s + bih1[j] + bhh1[j];
  if (t < G4_) bias2[t] = bih2[t] + bhh2[t];
}

// Persistent dual-LSTM recurrence; weights in f16 LDS; 2 WG/CU for TLP.
// WGs [0,128): layer1, 4u x 32b x 2kh.  WGs [128,384): layer2, 4u x 16b x 4kq,
// cat-k 1024 processed as two 512-k parts re-using one 16 KB staging buffer.
__global__ __launch_bounds__(256, 2) void k_rec(const float* __restrict__ Whh1,
                                                const float* __restrict__ Wih2,
                                                const float* __restrict__ Whh2,
                                                const float* __restrict__ xw1,
                                                const float* __restrict__ bias2,
                                                unsigned short* __restrict__ Hp,
                                                unsigned short* __restrict__ H1,
                                                unsigned int* __restrict__ bar) {
  __shared__ __align__(16) unsigned short sm[24704];   // 49408 B  (<= 65536 for 2/CU)
  unsigned long long* smu = (unsigned long long*)sm;
  const int wg = blockIdx.x, tid = threadIdx.x;
  unsigned dead = 0;
  unsigned long long* Hpu = (unsigned long long*)Hp;
  unsigned long long* H1u = (unsigned long long*)H1;

  if (wg < NWG_L1) {
    // -------- layer 1: 4u x 32b x 2kh; staging@0 (32KB), weights@16384 (16KB) --------
    const int b = tid & 31, kh = (tid >> 5) & 1, ul = tid >> 6;
    const int u = wg * 4 + ul;
    {   // preload Whh1 (4u x 4g = 16 rows x 512) -> f16 LDS, granule-swizzled
      const int rowid = tid >> 4;                // 0..15
      const int uw = rowid >> 2, g = rowid & 3;
      const int kt = (tid & 15) * 32;
      const float* src = Whh1 + ((size_t)(g * OUT_ + wg * 4 + uw)) * OUT_ + kt;
      #pragma unroll
      for (int e = 0; e < 32; ++e) {
        int k = kt + e, gr = k >> 3, sw = gr ^ ((gr >> 3) & 7);
        sm[16384 + (uw * 4 + g) * 512 + sw * 8 + (k & 7)] = f2h(src[e]);
      }
    }
    const float xb0 = xw1[b * G4_ + 0 * OUT_ + u];
    const float xb1 = xw1[b * G4_ + 1 * OUT_ + u];
    const float xb2 = xw1[b * G4_ + 2 * OUT_ + u];
    const float xb3 = xw1[b * G4_ + 3 * OUT_ + u];
    float creg = 0.f;

    for (int q = 0; q < T_; ++q) {
      // stage h(q): [32][512] f16, granule+row swizzled (R7-proven pattern)
      unsigned long long v[16];
      const unsigned long long* src = Hpu + (size_t)(q & 1) * 4096;
      #pragma unroll
      for (int i = 0; i < 16; ++i) v[i] = ld8(src + i * 256 + tid);
      #pragma unroll
      for (int i = 0; i < 16; ++i) {
        int j8 = i * 256 + tid;
        int row = j8 >> 7, col8 = j8 & 127, g8 = col8 >> 1, half = col8 & 1;
        int sw = g8 ^ ((g8 >> 3) & 7) ^ (row & 7);
        smu[row * 128 + sw * 2 + half] = v[i];
      }
      __syncthreads();

      float s0 = 0.f, s1 = 0.f, s2 = 0.f, s3 = 0.f;
      #pragma unroll 4
      for (int i = 0; i < 32; ++i) {
        int g8 = kh * 32 + i;
        int swc = g8 ^ ((g8 >> 3) & 7);
        h8 hv = *(const h8*)&sm[b * 512 + (swc ^ (b & 7)) * 8];
        const unsigned short* wb = &sm[16384 + (ul * 4) * 512 + swc * 8];
        h8 w0 = *(const h8*)(wb);
        h8 w1 = *(const h8*)(wb + 512);
        h8 w2 = *(const h8*)(wb + 1024);
        h8 w3 = *(const h8*)(wb + 1536);
        s0 = dot8(hv, w0, s0); s1 = dot8(hv, w1, s1);
        s2 = dot8(hv, w2, s2); s3 = dot8(hv, w3, s3);
      }
      s0 += __shfl_xor(s0, 32, 64); s1 += __shfl_xor(s1, 32, 64);
      s2 += __shfl_xor(s2, 32, 64); s3 += __shfl_xor(s3, 32, 64);
      float p0 = xb0 + s0, p1 = xb1 + s1, p2 = xb2 + s2, p3 = xb3 + s3;
      float ig = sigmf(p0), fg = sigmf(p1), gg = tanhf(p2), og = sigmf(p3);
      creg = fmaf(fg, creg, ig * gg);
      float h = og * tanhf(creg);
      if (kh == 0) sm[24576 + b * 4 + ul] = f2h(h);   // scratch (disjoint)
      __syncthreads();
      if (tid < 32) st8(Hpu + (size_t)((q + 1) & 1) * 4096 + (size_t)tid * 128 + wg,
                        smu[6144 + tid]);
      phase_barrier(bar, q, wg, &dead);
    }
  } else {
    // ---- layer 2: 4u x 16b x 4kq; staging@0 (16KB, reused), weights@8192 (32KB) ----
    const int wl = (wg - NWG_L1) >> 1;           // 0..127 (u-block)
    const int b0 = ((wg - NWG_L1) & 1) * 16;     // batch half
    const int bl = tid & 15, kq = (tid >> 4) & 3, ul = tid >> 6;
    const int u = wl * 4 + ul;
    {   // preload [Wih2 | Whh2] (16 rows x 1024 cat) -> f16 LDS
      const int rowid = tid >> 4, uw = rowid >> 2, g = rowid & 3;
      const int kt = (tid & 15) * 64;
      #pragma unroll
      for (int e = 0; e < 64; ++e) {
        int kc = kt + e;
        float wv = (kc < 512) ? Wih2[((size_t)(g * OUT_ + wl * 4 + uw)) * OUT_ + kc]
                              : Whh2[((size_t)(g * OUT_ + wl * 4 + uw)) * OUT_ + (kc - 512)];
        int gr = kc >> 3, sw = gr ^ ((gr >> 3) & 7);
        sm[8192 + (uw * 4 + g) * 1024 + sw * 8 + (kc & 7)] = f2h(wv);
      }
    }
    const float bs0 = bias2[0 * OUT_ + u], bs1 = bias2[1 * OUT_ + u];
    const float bs2 = bias2[2 * OUT_ + u], bs3 = bias2[3 * OUT_ + u];
    float c1 = 0.f;

    phase_barrier(bar, 0, wg, &dead);
    for (int q = 1; q <= T_; ++q) {
      float s0 = 0.f, s1 = 0.f, s2 = 0.f, s3 = 0.f;
      #pragma unroll
      for (int p = 0; p < 2; ++p) {
        // stage part p: rows [b0,b0+16) of (p==0 ? h(q) : h1(q-1)), 16 rows x 512
        const unsigned long long* srcp = p ? (H1u + (size_t)(q - 1) * 4096)
                                           : (Hpu + (size_t)(q & 1) * 4096);
        unsigned long long v[8];
        #pragma unroll
        for (int i = 0; i < 8; ++i) {
          int j8 = i * 256 + tid;
          int row = j8 >> 7, col8 = j8 & 127;
          v[i] = ld8(srcp + (size_t)(b0 + row) * 128 + col8);
        }
        #pragma unroll
        for (int i = 0; i < 8; ++i) {
          int j8 = i * 256 + tid;
          int row = j8 >> 7, col8 = j8 & 127, g8 = col8 >> 1, half = col8 & 1;
          int sw = g8 ^ ((g8 >> 3) & 7) ^ (row & 7);
          smu[row * 128 + sw * 2 + half] = v[i];
        }
        __syncthreads();

        #pragma unroll 4
        for (int i = 0; i < 16; ++i) {
          int g = kq * 16 + i;
          int sws = g ^ ((g >> 3) & 7);
          h8 xv = *(const h8*)&sm[bl * 512 + (sws ^ (bl & 7)) * 8];
          int gr = p * 64 + kq * 16 + i;
          int sww = gr ^ ((gr >> 3) & 7);
          const unsigned short* wb = &sm[8192 + (ul * 4) * 1024 + sww * 8];
          h8 w0 = *(const h8*)(wb);
          h8 w1 = *(const h8*)(wb + 1024);
          h8 w2 = *(const h8*)(wb + 2048);
          h8 w3 = *(const h8*)(wb + 3072);
          s0 = dot8(xv, w0, s0); s1 = dot8(xv, w1, s1);
          s2 = dot8(xv, w2, s2); s3 = dot8(xv, w3, s3);
        }
        __syncthreads();   // staging reuse guard (p=0) / pre-scratch guard (p=1)
      }
      s0 += __shfl_xor(s0, 16, 64); s0 += __shfl_xor(s0, 32, 64);
      s1 += __shfl_xor(s1, 16, 64); s1 += __shfl_xor(s1, 32, 64);
      s2 += __shfl_xor(s2, 16, 64); s2 += __shfl_xor(s2, 32, 64);
      s3 += __shfl_xor(s3, 16, 64); s3 += __shfl_xor(s3, 32, 64);
      float p0 = bs0 + s0, p1 = bs1 + s1, p2 = bs2 + s2, p3 = bs3 + s3;
      float ig = sigmf(p0), fg = sigmf(p1), gg = tanhf(p2), og = sigmf(p3);
      c1 = fmaf(fg, c1, ig * gg);
      float h1v = og * tanhf(c1);
      if (kq == 0) sm[24576 + bl * 4 + ul] = f2h(h1v);   // scratch (disjoint)
      __syncthreads();
      if (tid < 16) st8(H1u + (size_t)q * 4096 + (size_t)(b0 + tid) * 128 + wl,
                        smu[6144 + tid]);
      if (q < T_) phase_barrier(bar, q, wg, &dead);
    }
  }
}

// out[b][n][w][v] = h1(step s=n*32+w)·W_f[v] + b_f[v];  A row m = s*32+b -> H1 flat row m+32
__global__ __launch_bounds__(256, 1) void k_gemm(const unsigned short* __restrict__ H1,
                                                 const float* __restrict__ Wf,
                                                 const float* __restrict__ bfv,
                                                 float* __restrict__ out) {
  __shared__ __align__(16) float As[128 * 36];
  __shared__ __align__(16) float Bs[128 * 36];
  const int mt = blockIdx.x, nt = blockIdx.y, tid = threadIdx.x;
  const int tm = tid >> 4, tv = tid & 15;
  float acc[8][8];
  #pragma unroll
  for (int i = 0; i < 8; ++i)
    #pragma unroll
    for (int j = 0; j < 8; ++j) acc[i][j] = 0.f;

  const unsigned short* Abase = H1 + (size_t)(32 + mt * 128) * OUT_;

  for (int k0 = 0; k0 < OUT_; k0 += 32) {
    #pragma unroll
    for (int j = 0; j < 2; ++j) {
      int a8 = j * 256 + tid;
      int r = a8 >> 2, kp = (a8 & 3) * 8;
      h8 hv = *(const h8*)(Abase + (size_t)r * OUT_ + k0 + kp);
      float4 f0 = { (float)hv[0], (float)hv[1], (float)hv[2], (float)hv[3] };
      float4 f1 = { (float)hv[4], (float)hv[5], (float)hv[6], (float)hv[7] };
      *(float4*)&As[r * 36 + kp]     = f0;
      *(float4*)&As[r * 36 + kp + 4] = f1;
    }
    #pragma unroll
    for (int j = 0; j < 4; ++j) {
      int b4 = j * 256 + tid;
      int r = b4 >> 3, kp = (b4 & 7) * 4;
      int vv = nt * 128 + r;
      float4 fv = {0, 0, 0, 0};
      if (vv < VOCAB_) fv = *(const float4*)(Wf + (size_t)vv * OUT_ + k0 + kp);
      *(float4*)&Bs[r * 36 + kp] = fv;
    }
    __syncthreads();

    #pragma unroll
    for (int kk = 0; kk < 32; kk += 4) {
      float4 af[8];
      #pragma unroll
      for (int i = 0; i < 8; ++i) af[i] = *(const float4*)&As[(tm + i * 16) * 36 + kk];
      #pragma unroll
      for (int j = 0; j < 8; ++j) {
        float4 bv = *(const float4*)&Bs[(tv + j * 16) * 36 + kk];
        #pragma unroll
        for (int i = 0; i < 8; ++i) {
          acc[i][j] = fmaf(af[i].x, bv.x, acc[i][j]);
          acc[i][j] = fmaf(af[i].y, bv.y, acc[i][j]);
          acc[i][j] = fmaf(af[i].z, bv.z, acc[i][j]);
          acc[i][j] = fmaf(af[i].w, bv.w, acc[i][j]);
        }
      }
    }
    __syncthreads();
  }

  #pragma unroll
  for (int j = 0; j < 8; ++j) {
    int vv = nt * 128 + tv + j * 16;
    if (vv >= VOCAB_) continue;
    float bias = bfv[vv];
    #pragma unroll
    for (int i = 0; i < 8; ++i) {
      int m = mt * 128 + tm + i * 16;
      int bb = m & 31, s = m >> 5;
      out[(size_t)(bb * 256 + s) * VOCAB_ + vv] = acc[i][j] + bias;
    }
  }
}

extern "C" void kernel_launch(void* const* d_in, const int* in_sizes, int n_in,
                              void* d_out, int out_size, void* d_ws, size_t ws_size,
                              hipStream_t stream) {
  const float* lf   = (const float*)d_in[0];
  const float* Wih1 = (const float*)d_in[5];
  const float* Whh1 = (const float*)d_in[6];
  const float* bih1 = (const float*)d_in[7];
  const float* bhh1 = (const float*)d_in[8];
  const float* Wih2 = (const float*)d_in[9];
  const float* Whh2 = (const float*)d_in[10];
  const float* bih2 = (const float*)d_in[11];
  const float* bhh2 = (const float*)d_in[12];
  const float* Wf   = (const float*)d_in[13];
  const float* bfv  = (const float*)d_in[14];
  float* out = (float*)d_out;
  char* ws = (char*)d_ws;

  unsigned int*   bar  = (unsigned int*)(ws + OFF_BAR);
  float*          x    = (float*)(ws + OFF_X);
  float*          xw1  = (float*)(ws + OFF_XW1);
  float*          b2   = (float*)(ws + OFF_B2);
  unsigned short* Hp   = (unsigned short*)(ws + OFF_HP);
  unsigned short* H1   = (unsigned short*)(ws + OFF_H1);

  (void)hipMemsetAsync(bar, 0, BAR_BYTES_, stream);
  (void)hipMemsetAsync(Hp,  0, 2 * B_ * OUT_ * 2, stream);   // h(0)=0, both frames
  (void)hipMemsetAsync(H1,  0, H1_BYTES_, stream);           // all frames (fail signature)

  k_rowsum<<<128, 256, 0, stream>>>(lf, x);
  k_xw1<<<256, 256, 0, stream>>>(x, Wih1, bih1, bhh1, bih2, bhh2, xw1, b2);

  void* kargs[] = {(void*)&Whh1, (void*)&Wih2, (void*)&Whh2, (void*)&xw1,
                   (void*)&b2, (void*)&Hp, (void*)&H1, (void*)&bar};
  hipError_t cerr = hipLaunchCooperativeKernel((void*)k_rec, dim3(NWG_REC), dim3(256),
                                               kargs, 0, stream);
  if (cerr != hipSuccess) {
    // fallback: plain launch (2 WG/CU occupancy -> all 384 co-resident; watchdog guards)
    k_rec<<<NWG_REC, 256, 0, stream>>>(Whh1, Wih2, Whh2, xw1, b2, Hp, H1, bar);
  }

  k_gemm<<<dim3(64, 26), 256, 0, stream>>>(H1, Wf, bfv, out);
}

// Round 9
// 2084.021 us; speedup vs baseline: 2.0975x; 2.0975x over previous
//
#include <hip/hip_runtime.h>
#include <hip/hip_bf16.h>

// Problem constants
#define B_     32
#define DL_    1024
#define L_     196
#define OUT_   512
#define G4_    2048
#define T_     256      // NS*NW total timesteps
#define VOCAB_ 3266
#define NWG_REC 64      // 32 layer-1 WGs + 32 layer-2 WGs (MFMA design)
#define NWG_L1  32
#define NSLOT_  16
#define SLOT_TGT_ (NWG_REC / NSLOT_)   // 4 arrivals per slot
#define SLOT_STRIDE_ 16                // one 64B line per slot

// workspace layout (bytes)
#define OFF_BAR 0
#define BAR_BYTES_ (T_ * NSLOT_ * SLOT_STRIDE_ * 4)
#define OFF_X   (OFF_BAR + BAR_BYTES_)              // [32][1024] f32
#define OFF_XW1 (OFF_X + B_*DL_*4)                  // [32][2048] f32
#define OFF_B2  (OFF_XW1 + B_*G4_*4)                // [2048] f32
#define OFF_HP  (OFF_B2 + G4_*4)                    // ping-pong h: [2][32][512] f16
#define OFF_H1  (OFF_HP + 2*B_*OUT_*2)              // [257][32][512] f16
#define H1_BYTES_ ((size_t)(T_+1)*B_*OUT_*2)

typedef _Float16 half8 __attribute__((ext_vector_type(8)));
typedef float floatx4 __attribute__((ext_vector_type(4)));

__device__ __forceinline__ float sigmf(float v) { return 1.0f / (1.0f + __expf(-v)); }

__device__ __forceinline__ unsigned short f2h(float f) {
  union { _Float16 h; unsigned short u; } c;
  c.h = (_Float16)f;
  return c.u;
}

// 8 consecutive f32 -> half8 (weight fragment conversion, done once)
__device__ __forceinline__ half8 ldw8(const float* p) {
  float4 q0 = *(const float4*)p;
  float4 q1 = *(const float4*)(p + 4);
  half8 r;
  r[0] = (_Float16)q0.x; r[1] = (_Float16)q0.y; r[2] = (_Float16)q0.z; r[3] = (_Float16)q0.w;
  r[4] = (_Float16)q1.x; r[5] = (_Float16)q1.y; r[6] = (_Float16)q1.z; r[7] = (_Float16)q1.w;
  return r;
}

// coherent (bypass L1/L2 -> L3 coherent point) 8B load/store — proven R4/R7/R8
__device__ __forceinline__ unsigned long long ld8(const unsigned long long* p) {
  return __hip_atomic_load(p, __ATOMIC_RELAXED, __HIP_MEMORY_SCOPE_AGENT);
}
__device__ __forceinline__ void st8(unsigned long long* p, unsigned long long v) {
  __hip_atomic_store(p, v, __ATOMIC_RELAXED, __HIP_MEMORY_SCOPE_AGENT);
}

// Fence-free phase barrier; watchdog frees GPU on co-residency loss.
__device__ __forceinline__ void phase_barrier(unsigned int* bar, int q, int wg, unsigned* dead) {
  const int tid = threadIdx.x;
  if (tid == 0) {
    asm volatile("s_waitcnt vmcnt(0)" ::: "memory");
    __hip_atomic_fetch_add(&bar[(q * NSLOT_ + (wg & (NSLOT_ - 1))) * SLOT_STRIDE_], 1u,
                           __ATOMIC_RELAXED, __HIP_MEMORY_SCOPE_AGENT);
  }
  if (tid < NSLOT_ && !*dead) {
    unsigned polls = 0;
    while (__hip_atomic_load(&bar[(q * NSLOT_ + tid) * SLOT_STRIDE_], __ATOMIC_RELAXED,
                             __HIP_MEMORY_SCOPE_AGENT) < (unsigned)SLOT_TGT_) {
      __builtin_amdgcn_s_sleep(2);
      if (++polls > 10000000u) { *dead = 1; break; }
    }
  }
  __syncthreads();
}

// x[b][d] = sum_i local_features[b][d][i]
__global__ __launch_bounds__(256) void k_rowsum(const float* __restrict__ lf, float* __restrict__ x) {
  int t = blockIdx.x * 256 + threadIdx.x;
  const float4* p = (const float4*)(lf + (size_t)t * L_);
  float s = 0.f;
  #pragma unroll
  for (int i = 0; i < 49; ++i) { float4 v = p[i]; s += (v.x + v.y) + (v.z + v.w); }
  x[t] = s;
}

// xw1[b][j] = x[b]·W_ih1[j] + b_ih1[j] + b_hh1[j];  bias2[j] = b_ih2[j]+b_hh2[j]
__global__ __launch_bounds__(256) void k_xw1(const float* __restrict__ x, const float* __restrict__ Wih1,
                                             const float* __restrict__ bih1, const float* __restrict__ bhh1,
                                             const float* __restrict__ bih2, const float* __restrict__ bhh2,
                                             float* __restrict__ xw1, float* __restrict__ bias2) {
  int t = blockIdx.x * 256 + threadIdx.x;
  int b = t >> 11, j = t & (G4_ - 1);
  const float4* xp = (const float4*)(x + (size_t)b * DL_);
  const float4* wp = (const float4*)(Wih1 + (size_t)j * DL_);
  float s = 0.f;
  #pragma unroll 8
  for (int i = 0; i < DL_ / 4; ++i) {
    float4 a = xp[i], w = wp[i];
    s += a.x * w.x + a.y * w.y + a.z * w.z + a.w * w.w;
  }
  xw1[t] = s + bih1[j] + bhh1[j];
  if (t < G4_) bias2[t] = bih2[t] + bhh2[t];
}

// Persistent dual-LSTM recurrence on MFMA. Weights live in VGPRs as A-fragments
// (interleaved rows r=4*u_local+gate so D gives all 4 gates of (b,u) in one lane's
// 4 acc regs). h is operand B, staged per-WG in XOR-swizzled LDS.
// WGs [0,32): layer1 (4u/wave, K=512). WGs [32,64): layer2 (4u/wave, cat-K=1024).
__global__ __launch_bounds__(256, 1) void k_rec(const float* __restrict__ Whh1,
                                                const float* __restrict__ Wih2,
                                                const float* __restrict__ Whh2,
                                                const float* __restrict__ xw1,
                                                const float* __restrict__ bias2,
                                                unsigned short* __restrict__ Hp,
                                                unsigned short* __restrict__ H1,
                                                unsigned int* __restrict__ bar) {
  __shared__ __align__(16) unsigned short sm[33280];   // 66560 B (staging + 1KB scratch)
  unsigned long long* smu = (unsigned long long*)sm;
  const int wg = blockIdx.x, tid = threadIdx.x;
  unsigned dead = 0;
  unsigned long long* Hpu = (unsigned long long*)Hp;
  unsigned long long* H1u = (unsigned long long*)H1;
  const int wv = tid >> 6, l = tid & 63, lr = l & 15, kg = l >> 4;
  const int swz = lr & 7;

  if (wg < NWG_L1) {
    // ------------------- layer 1: u0 = wg*16 + wv*4 -------------------
    const int u0 = (wg * 4 + wv) * 4;
    half8 wf[16];
    {
      const int j = (lr & 3) * 512 + u0 + (lr >> 2);   // interleaved W' row
      const float* wr = Whh1 + (size_t)j * OUT_ + kg * 8;
      #pragma unroll
      for (int kt = 0; kt < 16; ++kt) wf[kt] = ldw8(wr + kt * 32);
    }
    floatx4 xb0, xb1;
    #pragma unroll
    for (int g = 0; g < 4; ++g) {
      xb0[g] = xw1[lr * G4_ + g * OUT_ + u0 + kg];
      xb1[g] = xw1[(16 + lr) * G4_ + g * OUT_ + u0 + kg];
    }
    float cs0 = 0.f, cs1 = 0.f;

    for (int q = 0; q < T_; ++q) {
      // stage h(q) [32][512] f16 -> LDS, 16B-chunk XOR swizzle
      const unsigned long long* src = Hpu + (size_t)(q & 1) * 4096;
      #pragma unroll
      for (int hb = 0; hb < 2; ++hb) {
        unsigned long long v[8];
        #pragma unroll
        for (int i = 0; i < 8; ++i) v[i] = ld8(src + (size_t)((hb * 8 + i) * 256 + tid));
        #pragma unroll
        for (int i = 0; i < 8; ++i) {
          int w = (hb * 8 + i) * 256 + tid;
          int b = w >> 7, c8 = w & 127, k8 = c8 >> 1, hf = c8 & 1;
          smu[b * 128 + ((k8 ^ (b & 7)) << 1) + hf] = v[i];
        }
      }
      __syncthreads();

      floatx4 a0 = xb0, a1 = xb1;
      #pragma unroll
      for (int kt = 0; kt < 16; ++kt) {
        int c0 = ((kt * 4 + kg) ^ swz) * 8;
        half8 h0 = *(const half8*)&sm[lr * 512 + c0];
        half8 h1 = *(const half8*)&sm[(16 + lr) * 512 + c0];
        a0 = __builtin_amdgcn_mfma_f32_16x16x32_f16(wf[kt], h0, a0, 0, 0, 0);
        a1 = __builtin_amdgcn_mfma_f32_16x16x32_f16(wf[kt], h1, a1, 0, 0, 0);
      }
      // epilogue: lane owns (b=lr|16+lr, u=u0+kg); regs = gates i,f,g,o
      {
        float i0 = sigmf(a0[0]), f0 = sigmf(a0[1]), g0 = tanhf(a0[2]), o0 = sigmf(a0[3]);
        cs0 = fmaf(f0, cs0, i0 * g0);
        float hv0 = o0 * tanhf(cs0);
        float i1 = sigmf(a1[0]), f1 = sigmf(a1[1]), g1 = tanhf(a1[2]), o1 = sigmf(a1[3]);
        cs1 = fmaf(f1, cs1, i1 * g1);
        float hv1 = o1 * tanhf(cs1);
        sm[16384 + lr * 16 + wv * 4 + kg] = f2h(hv0);
        sm[16384 + (16 + lr) * 16 + wv * 4 + kg] = f2h(hv1);
      }
      __syncthreads();
      if (tid < 128) {
        int b = tid >> 2, uw = tid & 3;
        st8(Hpu + (size_t)((q + 1) & 1) * 4096 + (size_t)b * 128 + wg * 4 + uw,
            smu[4096 + b * 4 + uw]);
      }
      __syncthreads();   // drain all waves' exchange stores before arrival
      phase_barrier(bar, q, wg, &dead);
    }
  } else {
    // ------------------- layer 2: cat-K = [h(q); h1(q-1)] -------------------
    const int wl = wg - NWG_L1;
    const int u0 = (wl * 4 + wv) * 4;
    half8 wf[32];
    {
      const int j = (lr & 3) * 512 + u0 + (lr >> 2);
      const float* wi = Wih2 + (size_t)j * OUT_ + kg * 8;
      const float* wh = Whh2 + (size_t)j * OUT_ + kg * 8;
      #pragma unroll
      for (int kt = 0; kt < 16; ++kt) wf[kt] = ldw8(wi + kt * 32);
      #pragma unroll
      for (int kt = 0; kt < 16; ++kt) wf[16 + kt] = ldw8(wh + kt * 32);
    }
    floatx4 bs;
    #pragma unroll
    for (int g = 0; g < 4; ++g) bs[g] = bias2[g * OUT_ + u0 + kg];
    float cs0 = 0.f, cs1 = 0.f;

    phase_barrier(bar, 0, wg, &dead);
    for (int q = 1; q <= T_; ++q) {
      const unsigned long long* sh  = Hpu + (size_t)(q & 1) * 4096;
      const unsigned long long* sh1 = H1u + (size_t)(q - 1) * 4096;
      #pragma unroll
      for (int hb = 0; hb < 4; ++hb) {
        unsigned long long v[8];
        #pragma unroll
        for (int i = 0; i < 8; ++i) {
          int w = (hb * 8 + i) * 256 + tid;
          int b = w >> 8, c8 = w & 255, k8 = c8 >> 1, hf = c8 & 1;
          v[i] = (k8 < 64) ? ld8(sh + (size_t)b * 128 + k8 * 2 + hf)
                           : ld8(sh1 + (size_t)b * 128 + (k8 - 64) * 2 + hf);
        }
        #pragma unroll
        for (int i = 0; i < 8; ++i) {
          int w = (hb * 8 + i) * 256 + tid;
          int b = w >> 8, c8 = w & 255, k8 = c8 >> 1, hf = c8 & 1;
          smu[b * 256 + ((k8 ^ (b & 7)) << 1) + hf] = v[i];
        }
      }
      __syncthreads();

      floatx4 a0 = bs, a1 = bs;
      #pragma unroll
      for (int kt = 0; kt < 32; ++kt) {
        int c0 = ((kt * 4 + kg) ^ swz) * 8;
        half8 h0 = *(const half8*)&sm[lr * 1024 + c0];
        half8 h1 = *(const half8*)&sm[(16 + lr) * 1024 + c0];
        a0 = __builtin_amdgcn_mfma_f32_16x16x32_f16(wf[kt], h0, a0, 0, 0, 0);
        a1 = __builtin_amdgcn_mfma_f32_16x16x32_f16(wf[kt], h1, a1, 0, 0, 0);
      }
      {
        float i0 = sigmf(a0[0]), f0 = sigmf(a0[1]), g0 = tanhf(a0[2]), o0 = sigmf(a0[3]);
        cs0 = fmaf(f0, cs0, i0 * g0);
        float hv0 = o0 * tanhf(cs0);
        float i1 = sigmf(a1[0]), f1 = sigmf(a1[1]), g1 = tanhf(a1[2]), o1 = sigmf(a1[3]);
        cs1 = fmaf(f1, cs1, i1 * g1);
        float hv1 = o1 * tanhf(cs1);
        sm[32768 + lr * 16 + wv * 4 + kg] = f2h(hv0);
        sm[32768 + (16 + lr) * 16 + wv * 4 + kg] = f2h(hv1);
      }
      __syncthreads();
      if (tid < 128) {
        int b = tid >> 2, uw = tid & 3;
        st8(H1u + (size_t)q * 4096 + (size_t)b * 128 + wl * 4 + uw,
            smu[8192 + b * 4 + uw]);
      }
      __syncthreads();
      if (q < T_) phase_barrier(bar, q, wg, &dead);
    }
  }
}

// out[b][n][w][v] = h1(step s=n*32+w)·W_f[v] + b_f[v];  A row m = s*32+b -> H1 flat row m+32
__global__ __launch_bounds__(256, 1) void k_gemm(const unsigned short* __restrict__ H1,
                                                 const float* __restrict__ Wf,
                                                 const float* __restrict__ bfv,
                                                 float* __restrict__ out) {
  __shared__ __align__(16) float As[128 * 36];
  __shared__ __align__(16) float Bs[128 * 36];
  const int mt = blockIdx.x, nt = blockIdx.y, tid = threadIdx.x;
  const int tm = tid >> 4, tv = tid & 15;
  float acc[8][8];
  #pragma unroll
  for (int i = 0; i < 8; ++i)
    #pragma unroll
    for (int j = 0; j < 8; ++j) acc[i][j] = 0.f;

  const unsigned short* Abase = H1 + (size_t)(32 + mt * 128) * OUT_;

  for (int k0 = 0; k0 < OUT_; k0 += 32) {
    #pragma unroll
    for (int j = 0; j < 2; ++j) {
      int a8 = j * 256 + tid;
      int r = a8 >> 2, kp = (a8 & 3) * 8;
      half8 hv = *(const half8*)(Abase + (size_t)r * OUT_ + k0 + kp);
      float4 f0 = { (float)hv[0], (float)hv[1], (float)hv[2], (float)hv[3] };
      float4 f1 = { (float)hv[4], (float)hv[5], (float)hv[6], (float)hv[7] };
      *(float4*)&As[r * 36 + kp]     = f0;
      *(float4*)&As[r * 36 + kp + 4] = f1;
    }
    #pragma unroll
    for (int j = 0; j < 4; ++j) {
      int b4 = j * 256 + tid;
      int r = b4 >> 3, kp = (b4 & 7) * 4;
      int vv = nt * 128 + r;
      float4 fv = {0, 0, 0, 0};
      if (vv < VOCAB_) fv = *(const float4*)(Wf + (size_t)vv * OUT_ + k0 + kp);
      *(float4*)&Bs[r * 36 + kp] = fv;
    }
    __syncthreads();

    #pragma unroll
    for (int kk = 0; kk < 32; kk += 4) {
      float4 af[8];
      #pragma unroll
      for (int i = 0; i < 8; ++i) af[i] = *(const float4*)&As[(tm + i * 16) * 36 + kk];
      #pragma unroll
      for (int j = 0; j < 8; ++j) {
        float4 bv = *(const float4*)&Bs[(tv + j * 16) * 36 + kk];
        #pragma unroll
        for (int i = 0; i < 8; ++i) {
          acc[i][j] = fmaf(af[i].x, bv.x, acc[i][j]);
          acc[i][j] = fmaf(af[i].y, bv.y, acc[i][j]);
          acc[i][j] = fmaf(af[i].z, bv.z, acc[i][j]);
          acc[i][j] = fmaf(af[i].w, bv.w, acc[i][j]);
        }
      }
    }
    __syncthreads();
  }

  #pragma unroll
  for (int j = 0; j < 8; ++j) {
    int vv = nt * 128 + tv + j * 16;
    if (vv >= VOCAB_) continue;
    float bias = bfv[vv];
    #pragma unroll
    for (int i = 0; i < 8; ++i) {
      int m = mt * 128 + tm + i * 16;
      int bb = m & 31, s = m >> 5;
      out[(size_t)(bb * 256 + s) * VOCAB_ + vv] = acc[i][j] + bias;
    }
  }
}

extern "C" void kernel_launch(void* const* d_in, const int* in_sizes, int n_in,
                              void* d_out, int out_size, void* d_ws, size_t ws_size,
                              hipStream_t stream) {
  const float* lf   = (const float*)d_in[0];
  const float* Wih1 = (const float*)d_in[5];
  const float* Whh1 = (const float*)d_in[6];
  const float* bih1 = (const float*)d_in[7];
  const float* bhh1 = (const float*)d_in[8];
  const float* Wih2 = (const float*)d_in[9];
  const float* Whh2 = (const float*)d_in[10];
  const float* bih2 = (const float*)d_in[11];
  const float* bhh2 = (const float*)d_in[12];
  const float* Wf   = (const float*)d_in[13];
  const float* bfv  = (const float*)d_in[14];
  float* out = (float*)d_out;
  char* ws = (char*)d_ws;

  unsigned int*   bar  = (unsigned int*)(ws + OFF_BAR);
  float*          x    = (float*)(ws + OFF_X);
  float*          xw1  = (float*)(ws + OFF_XW1);
  float*          b2   = (float*)(ws + OFF_B2);
  unsigned short* Hp   = (unsigned short*)(ws + OFF_HP);
  unsigned short* H1   = (unsigned short*)(ws + OFF_H1);

  (void)hipMemsetAsync(bar, 0, BAR_BYTES_, stream);
  (void)hipMemsetAsync(Hp,  0, 2 * B_ * OUT_ * 2, stream);   // h(0)=0, both frames
  (void)hipMemsetAsync(H1,  0, H1_BYTES_, stream);           // all frames (fail signature)

  k_rowsum<<<128, 256, 0, stream>>>(lf, x);
  k_xw1<<<256, 256, 0, stream>>>(x, Wih1, bih1, bhh1, bih2, bhh2, xw1, b2);

  void* kargs[] = {(void*)&Whh1, (void*)&Wih2, (void*)&Whh2, (void*)&xw1,
                   (void*)&b2, (void*)&Hp, (void*)&H1, (void*)&bar};
  hipError_t cerr = hipLaunchCooperativeKernel((void*)k_rec, dim3(NWG_REC), dim3(256),
                                               kargs, 0, stream);
  if (cerr != hipSuccess) {
    // fallback: plain launch (64 WGs trivially co-resident; watchdog guards)
    k_rec<<<NWG_REC, 256, 0, stream>>>(Whh1, Wih2, Whh2, xw1, b2, Hp, H1, bar);
  }

  k_gemm<<<dim3(64, 26), 256, 0, stream>>>(H1, Wf, bfv, out);
}

// Round 11
// 1211.458 us; speedup vs baseline: 3.6082x; 1.7203x over previous
//
#include <hip/hip_runtime.h>
#include <hip/hip_bf16.h>

// Problem constants
#define B_     32
#define DL_    1024
#define L_     196
#define OUT_   512
#define G4_    2048
#define T_     256
#define VOCAB_ 3266
#define NWG_L1  32
#define NWG_L2  64
#define NWG_REC (NWG_L1 + NWG_L2)   // 96
#define NSL_    8                   // slots per signal

// signal arrays: [257 phases][8 slots][16 u32 (64B line)]
#define SIG_STRIDE_ (NSL_ * 16)
#define SIG_BYTES_  (257 * SIG_STRIDE_ * 4)
#define OFF_SH   0
#define OFF_SH1  (SIG_BYTES_)
#define OFF_SR2  (2 * SIG_BYTES_)
#define OFF_X    (3 * SIG_BYTES_)
#define OFF_XW1  (OFF_X + B_*DL_*4)
#define OFF_B2   (OFF_XW1 + B_*G4_*4)
#define OFF_HP   (OFF_B2 + G4_*4)            // h ring: [4][32][512] f16
#define OFF_H1   (OFF_HP + 4*B_*OUT_*2)      // [257][32][512] f16

typedef _Float16 half8 __attribute__((ext_vector_type(8)));
typedef float floatx4 __attribute__((ext_vector_type(4)));

__device__ __forceinline__ float sigmf(float v) { return 1.0f / (1.0f + __expf(-v)); }

__device__ __forceinline__ unsigned short f2h(float f) {
  union { _Float16 h; unsigned short u; } c;
  c.h = (_Float16)f;
  return c.u;
}

__device__ __forceinline__ half8 ldw8(const float* p) {
  float4 q0 = *(const float4*)p;
  float4 q1 = *(const float4*)(p + 4);
  half8 r;
  r[0] = (_Float16)q0.x; r[1] = (_Float16)q0.y; r[2] = (_Float16)q0.z; r[3] = (_Float16)q0.w;
  r[4] = (_Float16)q1.x; r[5] = (_Float16)q1.y; r[6] = (_Float16)q1.z; r[7] = (_Float16)q1.w;
  return r;
}

__device__ __forceinline__ half8 pack8(float4 a, float4 b) {
  half8 r;
  r[0] = (_Float16)a.x; r[1] = (_Float16)a.y; r[2] = (_Float16)a.z; r[3] = (_Float16)a.w;
  r[4] = (_Float16)b.x; r[5] = (_Float16)b.y; r[6] = (_Float16)b.z; r[7] = (_Float16)b.w;
  return r;
}

// coherent (bypass L1/L2 -> L3 coherent point) 8B load/store — proven R4/R7/R9
__device__ __forceinline__ unsigned long long ld8(const unsigned long long* p) {
  return __hip_atomic_load(p, __ATOMIC_RELAXED, __HIP_MEMORY_SCOPE_AGENT);
}
__device__ __forceinline__ void st8(unsigned long long* p, unsigned long long v) {
  __hip_atomic_store(p, v, __ATOMIC_RELAXED, __HIP_MEMORY_SCOPE_AGENT);
}

__device__ __forceinline__ void sigadd(unsigned int* arr, int q, int wg) {
  __hip_atomic_fetch_add(&arr[q * SIG_STRIDE_ + (wg & (NSL_ - 1)) * 16], 1u,
                         __ATOMIC_RELAXED, __HIP_MEMORY_SCOPE_AGENT);
}

// single-slot poll; SHORT watchdog (~20 ms) so any stall ends as a visible,
// reportable failure — never an unresponsive container.
__device__ __forceinline__ void pollge(unsigned int* p, unsigned tgt, unsigned* dead) {
  if (*dead) return;
  unsigned polls = 0;
  while (__hip_atomic_load(p, __ATOMIC_RELAXED, __HIP_MEMORY_SCOPE_AGENT) < tgt) {
    __builtin_amdgcn_s_sleep(2);
    if (++polls > 400000u) { *dead = 1; break; }
  }
}

// x[b][d] = sum_i local_features[b][d][i]
__global__ __launch_bounds__(256) void k_rowsum(const float* __restrict__ lf, float* __restrict__ x) {
  int t = blockIdx.x * 256 + threadIdx.x;
  const float4* p = (const float4*)(lf + (size_t)t * L_);
  float s = 0.f;
  #pragma unroll
  for (int i = 0; i < 49; ++i) { float4 v = p[i]; s += (v.x + v.y) + (v.z + v.w); }
  x[t] = s;
}

// xw1[b][j] = x[b]·W_ih1[j] + b_ih1[j] + b_hh1[j];  bias2[j] = b_ih2[j]+b_hh2[j]
__global__ __launch_bounds__(256) void k_xw1(const float* __restrict__ x, const float* __restrict__ Wih1,
                                             const float* __restrict__ bih1, const float* __restrict__ bhh1,
                                             const float* __restrict__ bih2, const float* __restrict__ bhh2,
                                             float* __restrict__ xw1, float* __restrict__ bias2) {
  int t = blockIdx.x * 256 + threadIdx.x;
  int b = t >> 11, j = t & (G4_ - 1);
  const float4* xp = (const float4*)(x + (size_t)b * DL_);
  const float4* wp = (const float4*)(Wih1 + (size_t)j * DL_);
  float s = 0.f;
  #pragma unroll 8
  for (int i = 0; i < DL_ / 4; ++i) {
    float4 a = xp[i], w = wp[i];
    s += a.x * w.x + a.y * w.y + a.z * w.z + a.w * w.w;
  }
  xw1[t] = s + bih1[j] + bhh1[j];
  if (t < G4_) bias2[t] = bih2[t] + bhh2[t];
}

// Persistent dual-LSTM on MFMA with split producer/consumer signals (no global barrier).
// WGs [0,32): layer1 (16u x 32b, K=512). WGs [32,96): layer2 (16u x 16b, cat-K=1024).
// Signals: SH[q] = h(q) fully written (by L1, end of phase q-1, 4/slot);
//          SH1[q] = h1(q) fully written (by L2, 8/slot);
//          SR2[q] = L2 staged h(q) (8/slot) — anti-dep for the 4-deep Hp ring.
// sr1 (L1 self anti-dep) is REDUNDANT: SH[q] implies all L1 staged h(q-1) and earlier.
__global__ __launch_bounds__(256, 1) void k_rec(const float* __restrict__ Whh1,
                                                const float* __restrict__ Wih2,
                                                const float* __restrict__ Whh2,
                                                const float* __restrict__ xw1,
                                                const float* __restrict__ bias2,
                                                unsigned short* __restrict__ Hp,
                                                unsigned short* __restrict__ H1,
                                                unsigned int* __restrict__ sh,
                                                unsigned int* __restrict__ sh1,
                                                unsigned int* __restrict__ sr2) {
  __shared__ __align__(16) unsigned short sm[16896];   // 33792 B
  unsigned long long* smu = (unsigned long long*)sm;
  const int wg = blockIdx.x, tid = threadIdx.x;
  unsigned dead = 0;
  unsigned long long* Hpu = (unsigned long long*)Hp;
  unsigned long long* H1u = (unsigned long long*)H1;
  const int wv = tid >> 6, l = tid & 63, lr = l & 15, kg = l >> 4;
  const int swz = lr & 7;

  if (wg < NWG_L1) {
    // ---------------- layer 1 ----------------
    const int u0 = (wg * 4 + wv) * 4;
    half8 wf[16];
    {
      const int j = (lr & 3) * 512 + u0 + (lr >> 2);   // interleaved W' row (R9-proven)
      const float* wr = Whh1 + (size_t)j * OUT_ + kg * 8;
      #pragma unroll
      for (int kt = 0; kt < 16; ++kt) wf[kt] = ldw8(wr + kt * 32);
    }
    floatx4 xb0, xb1;
    #pragma unroll
    for (int g = 0; g < 4; ++g) {
      xb0[g] = xw1[lr * G4_ + g * OUT_ + u0 + kg];
      xb1[g] = xw1[(16 + lr) * G4_ + g * OUT_ + u0 + kg];
    }
    float cs0 = 0.f, cs1 = 0.f;

    for (int q = 0; q < T_; ++q) {
      // waits: SH[q] (h(q) complete); anti-dep SR2[q-3] (L2 staged h(q-3); 3-stale)
      if (q > 0) {
        if (tid < 8) pollge(&sh[q * SIG_STRIDE_ + tid * 16], 4, &dead);
        else if (tid >= 16 && tid < 24 && q >= 4)
          pollge(&sr2[(q - 3) * SIG_STRIDE_ + (tid - 16) * 16], 8, &dead);
        __syncthreads();
      }
      // stage h(q) [32][512] f16 from ring frame q&3 (16B-chunk XOR swizzle)
      const unsigned long long* src = Hpu + (size_t)(q & 3) * 4096;
      unsigned long long v[16];
      #pragma unroll
      for (int i = 0; i < 16; ++i) v[i] = ld8(src + i * 256 + tid);
      #pragma unroll
      for (int i = 0; i < 16; ++i) {
        int w = i * 256 + tid;
        int b = w >> 7, c8 = w & 127, k8 = c8 >> 1, hf = c8 & 1;
        smu[b * 128 + ((k8 ^ (b & 7)) << 1) + hf] = v[i];
      }
      __syncthreads();

      floatx4 a0 = xb0, a1 = xb1;
      #pragma unroll
      for (int kt = 0; kt < 16; ++kt) {
        int c0 = ((kt * 4 + kg) ^ swz) * 8;
        half8 h0 = *(const half8*)&sm[lr * 512 + c0];
        half8 h1 = *(const half8*)&sm[(16 + lr) * 512 + c0];
        a0 = __builtin_amdgcn_mfma_f32_16x16x32_f16(wf[kt], h0, a0, 0, 0, 0);
        a1 = __builtin_amdgcn_mfma_f32_16x16x32_f16(wf[kt], h1, a1, 0, 0, 0);
      }
      {
        float i0 = sigmf(a0[0]), f0 = sigmf(a0[1]), g0 = tanhf(a0[2]), o0 = sigmf(a0[3]);
        cs0 = fmaf(f0, cs0, i0 * g0);
        float hv0 = o0 * tanhf(cs0);
        float i1 = sigmf(a1[0]), f1 = sigmf(a1[1]), g1 = tanhf(a1[2]), o1 = sigmf(a1[3]);
        cs1 = fmaf(f1, cs1, i1 * g1);
        float hv1 = o1 * tanhf(cs1);
        sm[16384 + lr * 16 + wv * 4 + kg] = f2h(hv0);
        sm[16384 + (16 + lr) * 16 + wv * 4 + kg] = f2h(hv1);
      }
      __syncthreads();
      if (tid < 128) {
        int b = tid >> 2, uw = tid & 3;
        st8(Hpu + (size_t)((q + 1) & 3) * 4096 + (size_t)b * 128 + wg * 4 + uw,
            smu[4096 + b * 4 + uw]);
      }
      __syncthreads();                    // each wave drains its vmcnt -> stores visible
      if (tid == 0) sigadd(sh, q + 1, wg);
    }
  } else {
    // ---------------- layer 2 (b-split: 16u x 16b per WG) ----------------
    const int wl = wg - NWG_L1;          // 0..63
    const int ub = wl >> 1;              // u-block 0..31
    const int b0 = (wl & 1) * 16;
    const int u0 = (ub * 4 + wv) * 4;
    half8 wf[32];
    {
      const int j = (lr & 3) * 512 + u0 + (lr >> 2);
      const float* wi = Wih2 + (size_t)j * OUT_ + kg * 8;
      const float* wh = Whh2 + (size_t)j * OUT_ + kg * 8;
      #pragma unroll
      for (int kt = 0; kt < 16; ++kt) wf[kt] = ldw8(wi + kt * 32);
      #pragma unroll
      for (int kt = 0; kt < 16; ++kt) wf[16 + kt] = ldw8(wh + kt * 32);
    }
    floatx4 bs;
    #pragma unroll
    for (int g = 0; g < 4; ++g) bs[g] = bias2[g * OUT_ + u0 + kg];
    float cs = 0.f;

    for (int q = 1; q <= T_; ++q) {
      // waits: SH[q] (h(q) from L1); SH1[q-1] (own-layer h1 exchange)
      if (tid < 8) pollge(&sh[q * SIG_STRIDE_ + tid * 16], 4, &dead);
      else if (tid >= 8 && tid < 16 && q >= 2)
        pollge(&sh1[(q - 1) * SIG_STRIDE_ + (tid - 8) * 16], 8, &dead);
      __syncthreads();

      // stage cat rows [b0,b0+16): halves 0-511 <- h(q), 512-1023 <- h1(q-1)
      const unsigned long long* shp  = Hpu + (size_t)(q & 3) * 4096;
      const unsigned long long* sh1p = H1u + (size_t)(q - 1) * 4096;
      unsigned long long v[16];
      #pragma unroll
      for (int i = 0; i < 16; ++i) {
        int w = i * 256 + tid;
        int row = w >> 8, c8 = w & 255, k8 = c8 >> 1, hf = c8 & 1;
        v[i] = (k8 < 64) ? ld8(shp  + (size_t)(b0 + row) * 128 + (k8 << 1) + hf)
                         : ld8(sh1p + (size_t)(b0 + row) * 128 + ((k8 - 64) << 1) + hf);
      }
      #pragma unroll
      for (int i = 0; i < 16; ++i) {
        int w = i * 256 + tid;
        int row = w >> 8, c8 = w & 255, k8 = c8 >> 1, hf = c8 & 1;
        smu[row * 256 + ((k8 ^ (row & 7)) << 1) + hf] = v[i];
      }
      __syncthreads();
      if (tid == 0) sigadd(sr2, q, wg);   // done reading Hp frame q&3

      floatx4 a0 = bs;
      #pragma unroll
      for (int kt = 0; kt < 32; ++kt) {
        int c0 = ((kt * 4 + kg) ^ swz) * 8;
        half8 xv = *(const half8*)&sm[lr * 1024 + c0];
        a0 = __builtin_amdgcn_mfma_f32_16x16x32_f16(wf[kt], xv, a0, 0, 0, 0);
      }
      {
        float i0 = sigmf(a0[0]), f0 = sigmf(a0[1]), g0 = tanhf(a0[2]), o0 = sigmf(a0[3]);
        cs = fmaf(f0, cs, i0 * g0);
        float h1v = o0 * tanhf(cs);
        sm[16384 + lr * 16 + wv * 4 + kg] = f2h(h1v);
      }
      __syncthreads();
      if (tid < 64) {
        int row = tid >> 2, uw = tid & 3;
        st8(H1u + (size_t)q * 4096 + (size_t)(b0 + row) * 128 + ub * 4 + uw,
            smu[4096 + row * 4 + uw]);
      }
      __syncthreads();
      if (tid == 0) sigadd(sh1, q, wg);
    }
  }
}

// MFMA vocab projection: out[(b*256+s)][v] = h1_row(m=s*32+b)·Wf[v] + b_f[v]
__global__ __launch_bounds__(256, 2) void k_gemm(const unsigned short* __restrict__ H1,
                                                 const float* __restrict__ Wf,
                                                 const float* __restrict__ bfv,
                                                 float* __restrict__ out) {
  __shared__ __align__(16) unsigned short Asm[128 * 56];   // stride 56 halves (112B, 16B-aligned)
  __shared__ __align__(16) unsigned short Bsm[128 * 56];
  const int mt = blockIdx.x, nt = blockIdx.y, tid = threadIdx.x;
  const int wv = tid >> 6, l = tid & 63, lr = l & 15, kg = l >> 4;
  floatx4 acc[2][8];
  #pragma unroll
  for (int m = 0; m < 2; ++m)
    #pragma unroll
    for (int n = 0; n < 8; ++n) acc[m][n] = (floatx4){0.f, 0.f, 0.f, 0.f};

  const unsigned short* Abase = H1 + (size_t)(32 + mt * 128) * OUT_;
  const int r = tid >> 1, kh = (tid & 1) * 16;
  const int vr = nt * 128 + r;

  for (int k0 = 0; k0 < OUT_; k0 += 32) {
    // A tile: 128 rows x 32 k f16
    {
      const uint4* srcA = (const uint4*)(Abase + (size_t)r * OUT_ + k0 + kh);
      uint4 a0 = srcA[0], a1 = srcA[1];
      *(uint4*)&Asm[r * 56 + kh]     = a0;
      *(uint4*)&Asm[r * 56 + kh + 8] = a1;
    }
    // B tile: 128 vocab rows x 32 k, f32 -> f16 (zero past VOCAB_)
    {
      float4 f0 = {0,0,0,0}, f1 = f0, f2 = f0, f3 = f0;
      if (vr < VOCAB_) {
        const float4* wsrc = (const float4*)(Wf + (size_t)vr * OUT_ + k0 + kh);
        f0 = wsrc[0]; f1 = wsrc[1]; f2 = wsrc[2]; f3 = wsrc[3];
      }
      *(half8*)&Bsm[r * 56 + kh]     = pack8(f0, f1);
      *(half8*)&Bsm[r * 56 + kh + 8] = pack8(f2, f3);
    }
    __syncthreads();

    const int co = kg * 8;
    half8 a0f = *(const half8*)&Asm[(wv * 32 + lr) * 56 + co];
    half8 a1f = *(const half8*)&Asm[(wv * 32 + 16 + lr) * 56 + co];
    #pragma unroll
    for (int n = 0; n < 8; ++n) {
      half8 bf = *(const half8*)&Bsm[(n * 16 + lr) * 56 + co];
      acc[0][n] = __builtin_amdgcn_mfma_f32_16x16x32_f16(a0f, bf, acc[0][n], 0, 0, 0);
      acc[1][n] = __builtin_amdgcn_mfma_f32_16x16x32_f16(a1f, bf, acc[1][n], 0, 0, 0);
    }
    __syncthreads();
  }

  #pragma unroll
  for (int n = 0; n < 8; ++n) {
    int vcol = nt * 128 + n * 16 + lr;
    if (vcol >= VOCAB_) continue;
    float bias = bfv[vcol];
    #pragma unroll
    for (int m = 0; m < 2; ++m)
      #pragma unroll
      for (int g = 0; g < 4; ++g) {
        int mg = mt * 128 + wv * 32 + m * 16 + kg * 4 + g;
        int bb = mg & 31, s = mg >> 5;
        out[(size_t)(bb * 256 + s) * VOCAB_ + vcol] = acc[m][n][g] + bias;
      }
  }
}

extern "C" void kernel_launch(void* const* d_in, const int* in_sizes, int n_in,
                              void* d_out, int out_size, void* d_ws, size_t ws_size,
                              hipStream_t stream) {
  const float* lf   = (const float*)d_in[0];
  const float* Wih1 = (const float*)d_in[5];
  const float* Whh1 = (const float*)d_in[6];
  const float* bih1 = (const float*)d_in[7];
  const float* bhh1 = (const float*)d_in[8];
  const float* Wih2 = (const float*)d_in[9];
  const float* Whh2 = (const float*)d_in[10];
  const float* bih2 = (const float*)d_in[11];
  const float* bhh2 = (const float*)d_in[12];
  const float* Wf   = (const float*)d_in[13];
  const float* bfv  = (const float*)d_in[14];
  float* out = (float*)d_out;
  char* ws = (char*)d_ws;

  unsigned int*   sh   = (unsigned int*)(ws + OFF_SH);
  unsigned int*   sh1  = (unsigned int*)(ws + OFF_SH1);
  unsigned int*   sr2  = (unsigned int*)(ws + OFF_SR2);
  float*          x    = (float*)(ws + OFF_X);
  float*          xw1  = (float*)(ws + OFF_XW1);
  float*          b2   = (float*)(ws + OFF_B2);
  unsigned short* Hp   = (unsigned short*)(ws + OFF_HP);
  unsigned short* H1   = (unsigned short*)(ws + OFF_H1);

  (void)hipMemsetAsync(ws, 0, 3 * SIG_BYTES_, stream);       // all signal counters
  (void)hipMemsetAsync(Hp, 0, 4 * B_ * OUT_ * 2, stream);    // h ring (frame 0 = h(0) = 0)
  (void)hipMemsetAsync(H1, 0, B_ * OUT_ * 2, stream);        // h1(0) = 0

  k_rowsum<<<128, 256, 0, stream>>>(lf, x);
  k_xw1<<<256, 256, 0, stream>>>(x, Wih1, bih1, bhh1, bih2, bhh2, xw1, b2);

  void* kargs[] = {(void*)&Whh1, (void*)&Wih2, (void*)&Whh2, (void*)&xw1, (void*)&b2,
                   (void*)&Hp, (void*)&H1, (void*)&sh, (void*)&sh1, (void*)&sr2};
  hipError_t cerr = hipLaunchCooperativeKernel((void*)k_rec, dim3(NWG_REC), dim3(256),
                                               kargs, 0, stream);
  if (cerr != hipSuccess) {
    // fallback: plain launch (96 WGs trivially co-resident; short watchdog guards)
    k_rec<<<NWG_REC, 256, 0, stream>>>(Whh1, Wih2, Whh2, xw1, b2, Hp, H1, sh, sh1, sr2);
  }

  k_gemm<<<dim3(64, 26), 256, 0, stream>>>(H1, Wf, bfv, out);
}

// Round 13
// 1159.777 us; speedup vs baseline: 3.7690x; 1.0446x over previous
//
#include <hip/hip_runtime.h>
#include <hip/hip_bf16.h>

// Problem constants
#define B_     32
#define DL_    1024
#define L_     196
#define OUT_   512
#define G4_    2048
#define T_     256
#define VOCAB_ 3266
#define NWG_L1  16
#define NWG_L2  64
#define NWG_REC (NWG_L1 + NWG_L2)   // 80
#define NSL_    8

// signals: sh [257][8 slots][16], sh1 [257][2 halves][8][16], sr2 [257][8][16]
#define SIG_STRIDE_ (NSL_ * 16)
#define SIG_Q_      (257 * SIG_STRIDE_ * 4)
#define OFF_SH   0
#define OFF_SH1  (SIG_Q_)
#define OFF_SR2  (OFF_SH1 + 2 * SIG_Q_)
#define OFF_X    (OFF_SR2 + SIG_Q_)
#define OFF_XW1  (OFF_X + B_*DL_*4)
#define OFF_B2   (OFF_XW1 + B_*G4_*4)
#define OFF_HP   (OFF_B2 + G4_*4)            // h ring: [8][32][512] f16
#define OFF_H1   (OFF_HP + 8*B_*OUT_*2)      // [257][32][512] f16

typedef _Float16 half8 __attribute__((ext_vector_type(8)));
typedef float floatx4 __attribute__((ext_vector_type(4)));

__device__ __forceinline__ float sigmf(float v) { return 1.0f / (1.0f + __expf(-v)); }

__device__ __forceinline__ unsigned short f2h(float f) {
  union { _Float16 h; unsigned short u; } c;
  c.h = (_Float16)f;
  return c.u;
}

__device__ __forceinline__ half8 ldw8(const float* p) {
  float4 q0 = *(const float4*)p;
  float4 q1 = *(const float4*)(p + 4);
  half8 r;
  r[0] = (_Float16)q0.x; r[1] = (_Float16)q0.y; r[2] = (_Float16)q0.z; r[3] = (_Float16)q0.w;
  r[4] = (_Float16)q1.x; r[5] = (_Float16)q1.y; r[6] = (_Float16)q1.z; r[7] = (_Float16)q1.w;
  return r;
}

__device__ __forceinline__ half8 pack8(float4 a, float4 b) {
  half8 r;
  r[0] = (_Float16)a.x; r[1] = (_Float16)a.y; r[2] = (_Float16)a.z; r[3] = (_Float16)a.w;
  r[4] = (_Float16)b.x; r[5] = (_Float16)b.y; r[6] = (_Float16)b.z; r[7] = (_Float16)b.w;
  return r;
}

// coherent (bypass L1/L2 -> L3 coherent point) 8B load/store — proven R4/R7/R9/R11
__device__ __forceinline__ unsigned long long ld8(const unsigned long long* p) {
  return __hip_atomic_load(p, __ATOMIC_RELAXED, __HIP_MEMORY_SCOPE_AGENT);
}
__device__ __forceinline__ void st8(unsigned long long* p, unsigned long long v) {
  __hip_atomic_store(p, v, __ATOMIC_RELAXED, __HIP_MEMORY_SCOPE_AGENT);
}

__device__ __forceinline__ void sigraw(unsigned int* p) {
  __hip_atomic_fetch_add(p, 1u, __ATOMIC_RELAXED, __HIP_MEMORY_SCOPE_AGENT);
}

// short watchdog (~20 ms): any stall ends as a visible failure, never a hang
__device__ __forceinline__ void pollge(unsigned int* p, unsigned tgt, unsigned* dead) {
  if (*dead) return;
  unsigned polls = 0;
  while (__hip_atomic_load(p, __ATOMIC_RELAXED, __HIP_MEMORY_SCOPE_AGENT) < tgt) {
    __builtin_amdgcn_s_sleep(2);
    if (++polls > 400000u) { *dead = 1; break; }
  }
}

// x[b][d] = sum_i local_features[b][d][i]
__global__ __launch_bounds__(256) void k_rowsum(const float* __restrict__ lf, float* __restrict__ x) {
  int t = blockIdx.x * 256 + threadIdx.x;
  const float4* p = (const float4*)(lf + (size_t)t * L_);
  float s = 0.f;
  #pragma unroll
  for (int i = 0; i < 49; ++i) { float4 v = p[i]; s += (v.x + v.y) + (v.z + v.w); }
  x[t] = s;
}

// xw1[b][j] = x[b]·W_ih1[j] + b_ih1[j] + b_hh1[j];  bias2[j] = b_ih2[j]+b_hh2[j]
__global__ __launch_bounds__(256) void k_xw1(const float* __restrict__ x, const float* __restrict__ Wih1,
                                             const float* __restrict__ bih1, const float* __restrict__ bhh1,
                                             const float* __restrict__ bih2, const float* __restrict__ bhh2,
                                             float* __restrict__ xw1, float* __restrict__ bias2) {
  int t = blockIdx.x * 256 + threadIdx.x;
  int b = t >> 11, j = t & (G4_ - 1);
  const float4* xp = (const float4*)(x + (size_t)b * DL_);
  const float4* wp = (const float4*)(Wih1 + (size_t)j * DL_);
  float s = 0.f;
  #pragma unroll 8
  for (int i = 0; i < DL_ / 4; ++i) {
    float4 a = xp[i], w = wp[i];
    s += a.x * w.x + a.y * w.y + a.z * w.z + a.w * w.w;
  }
  xw1[t] = s + bih1[j] + bhh1[j];
  if (t < G4_) bias2[t] = bih2[t] + bhh2[t];
}

// Persistent dual-LSTM on MFMA, split signals, no global barrier.
// WGs [0,16): layer1 (32u/WG = 8u/wave, 32b, K=512).
// WGs [16,80): layer2 (16u x 16b, cat-K=1024), b-halves decoupled.
__global__ __launch_bounds__(256, 1) void k_rec(const float* __restrict__ Whh1,
                                                const float* __restrict__ Wih2,
                                                const float* __restrict__ Whh2,
                                                const float* __restrict__ xw1,
                                                const float* __restrict__ bias2,
                                                unsigned short* __restrict__ Hp,
                                                unsigned short* __restrict__ H1,
                                                unsigned int* __restrict__ sh,
                                                unsigned int* __restrict__ sh1,
                                                unsigned int* __restrict__ sr2) {
  __shared__ __align__(16) unsigned short sm[17408];   // 34816 B (32KB staging + 2KB scratch)
  unsigned long long* smu = (unsigned long long*)sm;
  const int wg = blockIdx.x, tid = threadIdx.x;
  unsigned dead = 0;
  unsigned long long* Hpu = (unsigned long long*)Hp;
  unsigned long long* H1u = (unsigned long long*)H1;
  const int wv = tid >> 6, l = tid & 63, lr = l & 15, kg = l >> 4;
  const int swz = lr & 7;

  if (wg < NWG_L1) {
    // ---------------- layer 1: 8u per wave (two 4-u fragment sets) ----------------
    const int u0 = (wg * 4 + wv) * 8;
    half8 wfa[16], wfb[16];
    {
      const int ja = (lr & 3) * 512 + u0 + (lr >> 2);        // set A: u0..u0+3
      const int jb = (lr & 3) * 512 + (u0 + 4) + (lr >> 2);  // set B: u0+4..u0+7
      const float* wra = Whh1 + (size_t)ja * OUT_ + kg * 8;
      const float* wrb = Whh1 + (size_t)jb * OUT_ + kg * 8;
      #pragma unroll
      for (int kt = 0; kt < 16; ++kt) { wfa[kt] = ldw8(wra + kt * 32); wfb[kt] = ldw8(wrb + kt * 32); }
    }
    floatx4 xb00, xb01, xb10, xb11;
    #pragma unroll
    for (int g = 0; g < 4; ++g) {
      xb00[g] = xw1[lr * G4_ + g * OUT_ + u0 + kg];
      xb01[g] = xw1[(16 + lr) * G4_ + g * OUT_ + u0 + kg];
      xb10[g] = xw1[lr * G4_ + g * OUT_ + u0 + 4 + kg];
      xb11[g] = xw1[(16 + lr) * G4_ + g * OUT_ + u0 + 4 + kg];
    }
    float cs00 = 0.f, cs01 = 0.f, cs10 = 0.f, cs11 = 0.f;

    for (int q = 0; q < T_; ++q) {
      // waits: SH[q] (h(q) complete, 2/slot); anti-dep SR2[q-7] (7-stale ring reuse)
      if (q > 0) {
        if (tid < 8) pollge(&sh[q * SIG_STRIDE_ + tid * 16], 2, &dead);
        else if (tid >= 16 && tid < 24 && q >= 8)
          pollge(&sr2[(q - 7) * SIG_STRIDE_ + (tid - 16) * 16], 8, &dead);
        __syncthreads();
      }
      // stage h(q) [32][512] f16 from ring frame q&7 (16B-chunk XOR swizzle)
      const unsigned long long* src = Hpu + (size_t)(q & 7) * 4096;
      unsigned long long v[16];
      #pragma unroll
      for (int i = 0; i < 16; ++i) v[i] = ld8(src + i * 256 + tid);
      #pragma unroll
      for (int i = 0; i < 16; ++i) {
        int w = i * 256 + tid;
        int b = w >> 7, c8 = w & 127, k8 = c8 >> 1, hf = c8 & 1;
        smu[b * 128 + ((k8 ^ (b & 7)) << 1) + hf] = v[i];
      }
      __syncthreads();

      floatx4 a00 = xb00, a01 = xb01, a10 = xb10, a11 = xb11;
      #pragma unroll
      for (int kt = 0; kt < 16; ++kt) {
        int c0 = ((kt * 4 + kg) ^ swz) * 8;
        half8 h0 = *(const half8*)&sm[lr * 512 + c0];
        half8 h1 = *(const half8*)&sm[(16 + lr) * 512 + c0];
        a00 = __builtin_amdgcn_mfma_f32_16x16x32_f16(wfa[kt], h0, a00, 0, 0, 0);
        a01 = __builtin_amdgcn_mfma_f32_16x16x32_f16(wfa[kt], h1, a01, 0, 0, 0);
        a10 = __builtin_amdgcn_mfma_f32_16x16x32_f16(wfb[kt], h0, a10, 0, 0, 0);
        a11 = __builtin_amdgcn_mfma_f32_16x16x32_f16(wfb[kt], h1, a11, 0, 0, 0);
      }
      {
        float i0, f0, g0, o0;
        i0 = sigmf(a00[0]); f0 = sigmf(a00[1]); g0 = tanhf(a00[2]); o0 = sigmf(a00[3]);
        cs00 = fmaf(f0, cs00, i0 * g0);
        sm[16384 + lr * 32 + wv * 8 + kg] = f2h(o0 * tanhf(cs00));
        i0 = sigmf(a01[0]); f0 = sigmf(a01[1]); g0 = tanhf(a01[2]); o0 = sigmf(a01[3]);
        cs01 = fmaf(f0, cs01, i0 * g0);
        sm[16384 + (16 + lr) * 32 + wv * 8 + kg] = f2h(o0 * tanhf(cs01));
        i0 = sigmf(a10[0]); f0 = sigmf(a10[1]); g0 = tanhf(a10[2]); o0 = sigmf(a10[3]);
        cs10 = fmaf(f0, cs10, i0 * g0);
        sm[16384 + lr * 32 + wv * 8 + 4 + kg] = f2h(o0 * tanhf(cs10));
        i0 = sigmf(a11[0]); f0 = sigmf(a11[1]); g0 = tanhf(a11[2]); o0 = sigmf(a11[3]);
        cs11 = fmaf(f0, cs11, i0 * g0);
        sm[16384 + (16 + lr) * 32 + wv * 8 + 4 + kg] = f2h(o0 * tanhf(cs11));
      }
      __syncthreads();
      {
        // exchange: 32 rows x 32u slice -> Hp[(q+1)&7], u-offset wg*32
        int row = tid >> 3, chunk = tid & 7;
        st8(Hpu + (size_t)((q + 1) & 7) * 4096 + (size_t)row * 128 + wg * 8 + chunk,
            smu[4096 + row * 8 + chunk]);
      }
      __syncthreads();                    // each wave drains its vmcnt -> stores visible
      if (tid == 0) sigraw(&sh[(q + 1) * SIG_STRIDE_ + (wg & 7) * 16]);
    }
  } else {
    // ---------------- layer 2: 16u x 16b per WG, b-halves decoupled ----------------
    const int wl = wg - NWG_L1;          // 0..63
    const int half = wl & 1;             // b-half
    const int ub = wl >> 1;              // u-block 0..31
    const int b0 = half * 16;
    const int u0 = (ub * 4 + wv) * 4;
    const int slot2 = (wl >> 1) & 7;     // 4 arrivals per slot per half
    half8 wf[32];
    {
      const int j = (lr & 3) * 512 + u0 + (lr >> 2);
      const float* wi = Wih2 + (size_t)j * OUT_ + kg * 8;
      const float* wh = Whh2 + (size_t)j * OUT_ + kg * 8;
      #pragma unroll
      for (int kt = 0; kt < 16; ++kt) wf[kt] = ldw8(wi + kt * 32);
      #pragma unroll
      for (int kt = 0; kt < 16; ++kt) wf[16 + kt] = ldw8(wh + kt * 32);
    }
    floatx4 bs;
    #pragma unroll
    for (int g = 0; g < 4; ++g) bs[g] = bias2[g * OUT_ + u0 + kg];
    float cs = 0.f;

    for (int q = 1; q <= T_; ++q) {
      // waits: SH[q] (h(q), 2/slot); SH1[q-1][own half] (4/slot)
      if (tid < 8) pollge(&sh[q * SIG_STRIDE_ + tid * 16], 2, &dead);
      else if (tid >= 8 && tid < 16 && q >= 2)
        pollge(&sh1[(q - 1) * 2 * SIG_STRIDE_ + half * SIG_STRIDE_ + (tid - 8) * 16], 4, &dead);
      __syncthreads();

      // stage cat rows [b0,b0+16): halves 0-511 <- h(q), 512-1023 <- h1(q-1)
      const unsigned long long* shp  = Hpu + (size_t)(q & 7) * 4096;
      const unsigned long long* sh1p = H1u + (size_t)(q - 1) * 4096;
      unsigned long long v[16];
      #pragma unroll
      for (int i = 0; i < 16; ++i) {
        int w = i * 256 + tid;
        int row = w >> 8, c8 = w & 255, k8 = c8 >> 1, hf = c8 & 1;
        v[i] = (k8 < 64) ? ld8(shp  + (size_t)(b0 + row) * 128 + (k8 << 1) + hf)
                         : ld8(sh1p + (size_t)(b0 + row) * 128 + ((k8 - 64) << 1) + hf);
      }
      #pragma unroll
      for (int i = 0; i < 16; ++i) {
        int w = i * 256 + tid;
        int row = w >> 8, c8 = w & 255, k8 = c8 >> 1, hf = c8 & 1;
        smu[row * 256 + ((k8 ^ (row & 7)) << 1) + hf] = v[i];
      }
      __syncthreads();
      if (tid == 0) sigraw(&sr2[q * SIG_STRIDE_ + (wg & 7) * 16]);   // staged h(q)

      floatx4 a0 = bs;
      #pragma unroll
      for (int kt = 0; kt < 32; ++kt) {
        int c0 = ((kt * 4 + kg) ^ swz) * 8;
        half8 xv = *(const half8*)&sm[lr * 1024 + c0];
        a0 = __builtin_amdgcn_mfma_f32_16x16x32_f16(wf[kt], xv, a0, 0, 0, 0);
      }
      {
        float i0 = sigmf(a0[0]), f0 = sigmf(a0[1]), g0 = tanhf(a0[2]), o0 = sigmf(a0[3]);
        cs = fmaf(f0, cs, i0 * g0);
        float h1v = o0 * tanhf(cs);
        sm[16384 + lr * 16 + wv * 4 + kg] = f2h(h1v);
      }
      __syncthreads();
      if (tid < 64) {
        int row = tid >> 2, uw = tid & 3;
        st8(H1u + (size_t)q * 4096 + (size_t)(b0 + row) * 128 + ub * 4 + uw,
            smu[4096 + row * 4 + uw]);   // FIX (R12 bug): scratch is at smu[4096], not [8192]
      }
      __syncthreads();
      if (tid == 0) sigraw(&sh1[q * 2 * SIG_STRIDE_ + half * SIG_STRIDE_ + slot2 * 16]);
    }
  }
}

// MFMA vocab projection: out[(b*256+s)][v] = h1_row(m=s*32+b)·Wf[v] + b_f[v]
__global__ __launch_bounds__(256, 2) void k_gemm(const unsigned short* __restrict__ H1,
                                                 const float* __restrict__ Wf,
                                                 const float* __restrict__ bfv,
                                                 float* __restrict__ out) {
  __shared__ __align__(16) unsigned short Asm[128 * 56];
  __shared__ __align__(16) unsigned short Bsm[128 * 56];
  const int mt = blockIdx.x, nt = blockIdx.y, tid = threadIdx.x;
  const int wv = tid >> 6, l = tid & 63, lr = l & 15, kg = l >> 4;
  floatx4 acc[2][8];
  #pragma unroll
  for (int m = 0; m < 2; ++m)
    #pragma unroll
    for (int n = 0; n < 8; ++n) acc[m][n] = (floatx4){0.f, 0.f, 0.f, 0.f};

  const unsigned short* Abase = H1 + (size_t)(32 + mt * 128) * OUT_;
  const int r = tid >> 1, kh = (tid & 1) * 16;
  const int vr = nt * 128 + r;

  for (int k0 = 0; k0 < OUT_; k0 += 32) {
    {
      const uint4* srcA = (const uint4*)(Abase + (size_t)r * OUT_ + k0 + kh);
      uint4 a0 = srcA[0], a1 = srcA[1];
      *(uint4*)&Asm[r * 56 + kh]     = a0;
      *(uint4*)&Asm[r * 56 + kh + 8] = a1;
    }
    {
      float4 f0 = {0,0,0,0}, f1 = f0, f2 = f0, f3 = f0;
      if (vr < VOCAB_) {
        const float4* wsrc = (const float4*)(Wf + (size_t)vr * OUT_ + k0 + kh);
        f0 = wsrc[0]; f1 = wsrc[1]; f2 = wsrc[2]; f3 = wsrc[3];
      }
      *(half8*)&Bsm[r * 56 + kh]     = pack8(f0, f1);
      *(half8*)&Bsm[r * 56 + kh + 8] = pack8(f2, f3);
    }
    __syncthreads();

    const int co = kg * 8;
    half8 a0f = *(const half8*)&Asm[(wv * 32 + lr) * 56 + co];
    half8 a1f = *(const half8*)&Asm[(wv * 32 + 16 + lr) * 56 + co];
    #pragma unroll
    for (int n = 0; n < 8; ++n) {
      half8 bf = *(const half8*)&Bsm[(n * 16 + lr) * 56 + co];
      acc[0][n] = __builtin_amdgcn_mfma_f32_16x16x32_f16(a0f, bf, acc[0][n], 0, 0, 0);
      acc[1][n] = __builtin_amdgcn_mfma_f32_16x16x32_f16(a1f, bf, acc[1][n], 0, 0, 0);
    }
    __syncthreads();
  }

  #pragma unroll
  for (int n = 0; n < 8; ++n) {
    int vcol = nt * 128 + n * 16 + lr;
    if (vcol >= VOCAB_) continue;
    float bias = bfv[vcol];
    #pragma unroll
    for (int m = 0; m < 2; ++m)
      #pragma unroll
      for (int g = 0; g < 4; ++g) {
        int mg = mt * 128 + wv * 32 + m * 16 + kg * 4 + g;
        int bb = mg & 31, s = mg >> 5;
        out[(size_t)(bb * 256 + s) * VOCAB_ + vcol] = acc[m][n][g] + bias;
      }
  }
}

extern "C" void kernel_launch(void* const* d_in, const int* in_sizes, int n_in,
                              void* d_out, int out_size, void* d_ws, size_t ws_size,
                              hipStream_t stream) {
  const float* lf   = (const float*)d_in[0];
  const float* Wih1 = (const float*)d_in[5];
  const float* Whh1 = (const float*)d_in[6];
  const float* bih1 = (const float*)d_in[7];
  const float* bhh1 = (const float*)d_in[8];
  const float* Wih2 = (const float*)d_in[9];
  const float* Whh2 = (const float*)d_in[10];
  const float* bih2 = (const float*)d_in[11];
  const float* bhh2 = (const float*)d_in[12];
  const float* Wf   = (const float*)d_in[13];
  const float* bfv  = (const float*)d_in[14];
  float* out = (float*)d_out;
  char* ws = (char*)d_ws;

  unsigned int*   sh   = (unsigned int*)(ws + OFF_SH);
  unsigned int*   sh1  = (unsigned int*)(ws + OFF_SH1);
  unsigned int*   sr2  = (unsigned int*)(ws + OFF_SR2);
  float*          x    = (float*)(ws + OFF_X);
  float*          xw1  = (float*)(ws + OFF_XW1);
  float*          b2   = (float*)(ws + OFF_B2);
  unsigned short* Hp   = (unsigned short*)(ws + OFF_HP);
  unsigned short* H1   = (unsigned short*)(ws + OFF_H1);

  (void)hipMemsetAsync(ws, 0, OFF_X, stream);                // all signal counters
  (void)hipMemsetAsync(Hp, 0, 8 * B_ * OUT_ * 2, stream);    // h ring (frame 0 = h(0) = 0)
  (void)hipMemsetAsync(H1, 0, B_ * OUT_ * 2, stream);        // h1(0) = 0

  k_rowsum<<<128, 256, 0, stream>>>(lf, x);
  k_xw1<<<256, 256, 0, stream>>>(x, Wih1, bih1, bhh1, bih2, bhh2, xw1, b2);

  void* kargs[] = {(void*)&Whh1, (void*)&Wih2, (void*)&Whh2, (void*)&xw1, (void*)&b2,
                   (void*)&Hp, (void*)&H1, (void*)&sh, (void*)&sh1, (void*)&sr2};
  hipError_t cerr = hipLaunchCooperativeKernel((void*)k_rec, dim3(NWG_REC), dim3(256),
                                               kargs, 0, stream);
  if (cerr != hipSuccess) {
    // fallback: plain launch (80 WGs trivially co-resident; short watchdog guards)
    k_rec<<<NWG_REC, 256, 0, stream>>>(Whh1, Wih2, Whh2, xw1, b2, Hp, H1, sh, sh1, sr2);
  }

  k_gemm<<<dim3(64, 26), 256, 0, stream>>>(H1, Wf, bfv, out);
}